// Round 4
// baseline (392.259 us; speedup 1.0000x reference)
//
#include <hip/hip_runtime.h>
#include <math.h>

#define FDIM 128

static inline size_t align512(size_t x) { return (x + 511) & ~((size_t)511); }

// ---- fused GEMM (out = X@W, unscaled) + optional degree histogram -------
// GEMM: 128 rows/block, 256 threads, thread = 4 rows x 16 cols.
// K processed in 4 chunks of 32; LDS = X[128][36] + W[32][128] = 34.8 KB.
// Extra blocks beyond gemm_blocks run the edge-count histogram.
#define TROWS 128
__global__ __launch_bounds__(256, 4) void gemm_count(const float* __restrict__ X,
                                                     const float* __restrict__ W,
                                                     float* __restrict__ out, int nrows,
                                                     int gemm_blocks,
                                                     const int* __restrict__ dst,
                                                     int* __restrict__ cnt, int ne) {
    __shared__ __align__(16) float Xl[TROWS * 36];   // one 32-k slice of X, pad->36
    __shared__ __align__(16) float Wl[32 * 128];     // one 32-k slice of W
    if ((int)blockIdx.x >= gemm_blocks) {
        int i = ((int)blockIdx.x - gemm_blocks) * 256 + threadIdx.x;
        if (i < ne) atomicAdd(&cnt[dst[i]], 1);
        return;
    }
    int tid = threadIdx.x;
    int row0 = blockIdx.x * TROWS;
    int nrow_t = min(TROWS, nrows - row0);

    int rg = tid >> 3;           // 0..31 -> rows rg, rg+32, rg+64, rg+96
    int c0 = (tid & 7) * 4;      // col base; cols c0 + 32*j
    float4 acc[4][4];
    #pragma unroll
    for (int a = 0; a < 4; a++)
        #pragma unroll
        for (int j = 0; j < 4; j++) acc[a][j] = make_float4(0.f, 0.f, 0.f, 0.f);

    for (int kc = 0; kc < 4; kc++) {
        __syncthreads();
        // stage X chunk: 32 cols of up to 128 rows (8 float4 per row)
        for (int idx = tid; idx < nrow_t * 8; idx += 256) {
            int r = idx >> 3, c4 = idx & 7;
            *(float4*)(&Xl[r * 36 + c4 * 4]) =
                *(const float4*)(X + (size_t)(row0 + r) * FDIM + kc * 32 + c4 * 4);
        }
        // stage W chunk: rows kc*32..+31 (1024 float4)
        for (int idx = tid; idx < 1024; idx += 256)
            *(float4*)(&Wl[idx * 4]) = *(const float4*)(W + (size_t)kc * 32 * FDIM + idx * 4);
        __syncthreads();
        #pragma unroll
        for (int k4 = 0; k4 < 8; k4++) {        // 4 k at a time
            float4 xr[4];
            #pragma unroll
            for (int a = 0; a < 4; a++)
                xr[a] = *(const float4*)(&Xl[(rg + 32 * a) * 36 + k4 * 4]);
            #pragma unroll
            for (int kk = 0; kk < 4; kk++) {
                float xs[4] = {0.f, 0.f, 0.f, 0.f};
                #pragma unroll
                for (int a = 0; a < 4; a++)
                    xs[a] = (kk == 0) ? xr[a].x : (kk == 1) ? xr[a].y
                          : (kk == 2) ? xr[a].z : xr[a].w;
                int k = k4 * 4 + kk;
                #pragma unroll
                for (int j = 0; j < 4; j++) {
                    float4 w = *(const float4*)(&Wl[k * FDIM + c0 + 32 * j]);
                    #pragma unroll
                    for (int a = 0; a < 4; a++) {
                        acc[a][j].x = fmaf(xs[a], w.x, acc[a][j].x);
                        acc[a][j].y = fmaf(xs[a], w.y, acc[a][j].y);
                        acc[a][j].z = fmaf(xs[a], w.z, acc[a][j].z);
                        acc[a][j].w = fmaf(xs[a], w.w, acc[a][j].w);
                    }
                }
            }
        }
    }
    #pragma unroll
    for (int a = 0; a < 4; a++) {
        int row = row0 + rg + 32 * a;
        if (row < nrows) {
            #pragma unroll
            for (int j = 0; j < 4; j++)
                *(float4*)(out + (size_t)row * FDIM + c0 + 32 * j) = acc[a][j];
        }
    }
}

// ---- Hierarchical exclusive scan ----------------------------------------
__global__ __launch_bounds__(256) void scan_block_sums(const int* __restrict__ cnt,
                                                       int* __restrict__ bsum, int n) {
    __shared__ int red[256];
    int tid = threadIdx.x;
    int idx = blockIdx.x * 256 + tid;
    red[tid] = (idx < n) ? cnt[idx] : 0;
    __syncthreads();
    for (int off = 128; off > 0; off >>= 1) {
        if (tid < off) red[tid] += red[tid + off];
        __syncthreads();
    }
    if (tid == 0) bsum[blockIdx.x] = red[0];
}

__global__ __launch_bounds__(1024) void scan_bsums(int* __restrict__ bsum, int nb) {
    __shared__ int sh[1024];
    int tid = threadIdx.x;
    int v = (tid < nb) ? bsum[tid] : 0;
    sh[tid] = v;
    __syncthreads();
    for (int off = 1; off < 1024; off <<= 1) {
        int t = (tid >= off) ? sh[tid - off] : 0;
        __syncthreads();
        sh[tid] += t;
        __syncthreads();
    }
    if (tid < nb) bsum[tid] = sh[tid] - v;   // exclusive
}

// also emits dinv = 1/sqrt(deg+1)
__global__ __launch_bounds__(256) void scan_final(const int* __restrict__ cnt,
                                                  const int* __restrict__ bsum,
                                                  int* __restrict__ rowptr,
                                                  int* __restrict__ cursor,
                                                  float* __restrict__ dinv, int n) {
    __shared__ int sh[256];
    int tid = threadIdx.x;
    int idx = blockIdx.x * 256 + tid;
    int c = (idx < n) ? cnt[idx] : 0;
    sh[tid] = c;
    __syncthreads();
    for (int off = 1; off < 256; off <<= 1) {
        int t = (tid >= off) ? sh[tid - off] : 0;
        __syncthreads();
        sh[tid] += t;
        __syncthreads();
    }
    if (idx < n) {
        int excl = sh[tid] - c + bsum[blockIdx.x];
        rowptr[idx] = excl;
        cursor[idx] = excl;
        dinv[idx] = 1.0f / sqrtf((float)(c + 1));
        if (idx == n - 1) rowptr[n] = excl + c;
    }
}

__global__ void scatter_kernel(const int* __restrict__ src, const int* __restrict__ dst,
                               int* __restrict__ cursor, int* __restrict__ csr_src, int ne) {
    int i = blockIdx.x * 256 + threadIdx.x;
    if (i < ne) {
        int d = dst[i];
        int pos = atomicAdd(&cursor[d], 1);
        csr_src[pos] = src[i];
    }
}

// ---- Aggregate + norm + bias + ELU --------------------------------------
// out[i] = elu( dinv[i] * ( sum_e dinv[s_e]*G[s_e] + dinv[i]*G[i] ) + b )
// 8 nodes/block, 32 threads/node, float4/lane, edge loop unrolled x8.
__global__ __launch_bounds__(256) void agg_elu(const float* __restrict__ G,
                                               const int* __restrict__ rowptr,
                                               const int* __restrict__ csr_src,
                                               const float* __restrict__ dinv,
                                               const float* __restrict__ bias,
                                               float* __restrict__ out, int n) {
    int node = blockIdx.x * 8 + (threadIdx.x >> 5);
    int c = threadIdx.x & 31;
    if (node >= n) return;
    const float4* G4 = (const float4*)G;
    int beg = rowptr[node], end = rowptr[node + 1];
    float dn = dinv[node];
    float4 self = G4[(size_t)node * 32 + c];
    float4 acc;
    acc.x = dn * self.x; acc.y = dn * self.y; acc.z = dn * self.z; acc.w = dn * self.w;
    int e = beg;
    for (; e + 7 < end; e += 8) {
        int s0 = csr_src[e],     s1 = csr_src[e + 1], s2 = csr_src[e + 2], s3 = csr_src[e + 3];
        int s4 = csr_src[e + 4], s5 = csr_src[e + 5], s6 = csr_src[e + 6], s7 = csr_src[e + 7];
        float d0 = dinv[s0], d1 = dinv[s1], d2 = dinv[s2], d3 = dinv[s3];
        float d4 = dinv[s4], d5 = dinv[s5], d6 = dinv[s6], d7 = dinv[s7];
        float4 v0 = G4[(size_t)s0 * 32 + c];
        float4 v1 = G4[(size_t)s1 * 32 + c];
        float4 v2 = G4[(size_t)s2 * 32 + c];
        float4 v3 = G4[(size_t)s3 * 32 + c];
        float4 v4 = G4[(size_t)s4 * 32 + c];
        float4 v5 = G4[(size_t)s5 * 32 + c];
        float4 v6 = G4[(size_t)s6 * 32 + c];
        float4 v7 = G4[(size_t)s7 * 32 + c];
        acc.x = fmaf(d0, v0.x, acc.x); acc.y = fmaf(d0, v0.y, acc.y);
        acc.z = fmaf(d0, v0.z, acc.z); acc.w = fmaf(d0, v0.w, acc.w);
        acc.x = fmaf(d1, v1.x, acc.x); acc.y = fmaf(d1, v1.y, acc.y);
        acc.z = fmaf(d1, v1.z, acc.z); acc.w = fmaf(d1, v1.w, acc.w);
        acc.x = fmaf(d2, v2.x, acc.x); acc.y = fmaf(d2, v2.y, acc.y);
        acc.z = fmaf(d2, v2.z, acc.z); acc.w = fmaf(d2, v2.w, acc.w);
        acc.x = fmaf(d3, v3.x, acc.x); acc.y = fmaf(d3, v3.y, acc.y);
        acc.z = fmaf(d3, v3.z, acc.z); acc.w = fmaf(d3, v3.w, acc.w);
        acc.x = fmaf(d4, v4.x, acc.x); acc.y = fmaf(d4, v4.y, acc.y);
        acc.z = fmaf(d4, v4.z, acc.z); acc.w = fmaf(d4, v4.w, acc.w);
        acc.x = fmaf(d5, v5.x, acc.x); acc.y = fmaf(d5, v5.y, acc.y);
        acc.z = fmaf(d5, v5.z, acc.z); acc.w = fmaf(d5, v5.w, acc.w);
        acc.x = fmaf(d6, v6.x, acc.x); acc.y = fmaf(d6, v6.y, acc.y);
        acc.z = fmaf(d6, v6.z, acc.z); acc.w = fmaf(d6, v6.w, acc.w);
        acc.x = fmaf(d7, v7.x, acc.x); acc.y = fmaf(d7, v7.y, acc.y);
        acc.z = fmaf(d7, v7.z, acc.z); acc.w = fmaf(d7, v7.w, acc.w);
    }
    for (; e < end; e++) {
        int s = csr_src[e];
        float d = dinv[s];
        float4 v = G4[(size_t)s * 32 + c];
        acc.x = fmaf(d, v.x, acc.x); acc.y = fmaf(d, v.y, acc.y);
        acc.z = fmaf(d, v.z, acc.z); acc.w = fmaf(d, v.w, acc.w);
    }
    float4 b = ((const float4*)bias)[c];
    float4 r;
    r.x = fmaf(dn, acc.x, b.x); r.y = fmaf(dn, acc.y, b.y);
    r.z = fmaf(dn, acc.z, b.z); r.w = fmaf(dn, acc.w, b.w);
    r.x = (r.x > 0.f) ? r.x : expm1f(r.x);
    r.y = (r.y > 0.f) ? r.y : expm1f(r.y);
    r.z = (r.z > 0.f) ? r.z : expm1f(r.z);
    r.w = (r.w > 0.f) ? r.w : expm1f(r.w);
    ((float4*)out)[(size_t)node * 32 + c] = r;
}

// ---- Global mean pool (contiguous nper-node graphs) ---------------------
__global__ __launch_bounds__(256) void pool_kernel(const float* __restrict__ H,
                                                   float* __restrict__ out,
                                                   int nper, int ngraphs) {
    __shared__ float tmp[128];
    int g = blockIdx.x;
    int f = threadIdx.x & 127;
    int half = threadIdx.x >> 7;
    if (g >= ngraphs) return;
    const float* base = H + (size_t)g * nper * FDIM;
    float acc = 0.f;
    for (int i = half; i < nper; i += 2) acc += base[(size_t)i * FDIM + f];
    if (half == 1) tmp[f] = acc;
    __syncthreads();
    if (half == 0) out[(size_t)g * FDIM + f] = (acc + tmp[f]) * (1.0f / (float)nper);
}

extern "C" void kernel_launch(void* const* d_in, const int* in_sizes, int n_in,
                              void* d_out, int out_size, void* d_ws, size_t ws_size,
                              hipStream_t stream) {
    const float* x  = (const float*)d_in[0];
    const float* W1 = (const float*)d_in[1];
    const float* b1 = (const float*)d_in[2];
    const float* W2 = (const float*)d_in[3];
    const float* b2 = (const float*)d_in[4];
    const int* edge_index = (const int*)d_in[5];
    float* out = (float*)d_out;

    int N = in_sizes[0] / FDIM;
    int E = in_sizes[5] / 2;
    int G = out_size / FDIM;
    int nper = N / G;
    const int* src = edge_index;
    const int* dst = edge_index + E;

    char* ws = (char*)d_ws;
    size_t off = 0;
    int* cnt = (int*)(ws + off);       off = align512(off + (size_t)N * 4);
    int* rowptr = (int*)(ws + off);    off = align512(off + (size_t)(N + 1) * 4);
    int* cursor = (int*)(ws + off);    off = align512(off + (size_t)N * 4);
    float* dinv = (float*)(ws + off);  off = align512(off + (size_t)N * 4);
    int* bsum = (int*)(ws + off);      off = align512(off + (size_t)1024 * 4);
    int* csr_src = (int*)(ws + off);   off = align512(off + (size_t)E * 4);
    float* bufA = (float*)(ws + off);  off = align512(off + (size_t)N * FDIM * 4);
    float* bufB = (float*)(ws + off);  off = align512(off + (size_t)N * FDIM * 4);
    (void)ws_size;

    int nb = (N + 255) / 256;                    // scan blocks (<=1024)
    int gemm_grid = (N + TROWS - 1) / TROWS;     // 391
    int cnt_grid = (E + 255) / 256;
    int agg_grid = (N + 7) / 8;

    hipMemsetAsync(cnt, 0, (size_t)N * 4, stream);
    // layer-1 GEMM fused with degree histogram (independent work)
    gemm_count<<<gemm_grid + cnt_grid, 256, 0, stream>>>(x, W1, bufA, N,
                                                         gemm_grid, dst, cnt, E);
    scan_block_sums<<<nb, 256, 0, stream>>>(cnt, bsum, N);
    scan_bsums<<<1, 1024, 0, stream>>>(bsum, nb);
    scan_final<<<nb, 256, 0, stream>>>(cnt, bsum, rowptr, cursor, dinv, N);
    scatter_kernel<<<(E + 255) / 256, 256, 0, stream>>>(src, dst, cursor, csr_src, E);

    agg_elu<<<agg_grid, 256, 0, stream>>>(bufA, rowptr, csr_src, dinv, b1, bufB, N);
    // layer-2 GEMM (no count part)
    gemm_count<<<gemm_grid, 256, 0, stream>>>(bufB, W2, bufA, N, gemm_grid, dst, cnt, 0);
    agg_elu<<<agg_grid, 256, 0, stream>>>(bufA, rowptr, csr_src, dinv, b2, bufB, N);
    pool_kernel<<<G, 256, 0, stream>>>(bufB, out, nper, G);
}

// Round 5
// 285.238 us; speedup vs baseline: 1.3752x; 1.3752x over previous
//
#include <hip/hip_runtime.h>
#include <math.h>

#define FDIM 128

static inline size_t align512(size_t x) { return (x + 511) & ~((size_t)511); }

// ---- fused GEMM (out = X@W, unscaled) + optional degree histogram -------
// GEMM: 128 rows/block, 256 threads, thread = 4 rows x 16 cols.
// K processed in 4 chunks of 32; LDS = X[128][36] + W[32][128] = 34.8 KB.
// NOTE: no min-waves clause — 64 f32 accumulators need ~110 VGPR; capping
// at 64 (R4) spilled acc to scratch (WRITE_SIZE 131MB, 119us).
#define TROWS 128
__global__ __launch_bounds__(256) void gemm_count(const float* __restrict__ X,
                                                  const float* __restrict__ W,
                                                  float* __restrict__ out, int nrows,
                                                  int gemm_blocks,
                                                  const int* __restrict__ dst,
                                                  int* __restrict__ cnt, int ne) {
    __shared__ __align__(16) float Xl[TROWS * 36];   // one 32-k slice of X, pad->36
    __shared__ __align__(16) float Wl[32 * 128];     // one 32-k slice of W
    if ((int)blockIdx.x >= gemm_blocks) {
        int i = ((int)blockIdx.x - gemm_blocks) * 256 + threadIdx.x;
        if (i < ne) atomicAdd(&cnt[dst[i]], 1);
        return;
    }
    int tid = threadIdx.x;
    int row0 = blockIdx.x * TROWS;
    int nrow_t = min(TROWS, nrows - row0);

    int rg = tid >> 3;           // 0..31 -> rows rg, rg+32, rg+64, rg+96
    int c0 = (tid & 7) * 4;      // col base; cols c0 + 32*j
    float4 acc[4][4];
    #pragma unroll
    for (int a = 0; a < 4; a++)
        #pragma unroll
        for (int j = 0; j < 4; j++) acc[a][j] = make_float4(0.f, 0.f, 0.f, 0.f);

    for (int kc = 0; kc < 4; kc++) {
        __syncthreads();
        // stage X chunk: 32 cols of up to 128 rows (8 float4 per row)
        for (int idx = tid; idx < nrow_t * 8; idx += 256) {
            int r = idx >> 3, c4 = idx & 7;
            *(float4*)(&Xl[r * 36 + c4 * 4]) =
                *(const float4*)(X + (size_t)(row0 + r) * FDIM + kc * 32 + c4 * 4);
        }
        // stage W chunk: rows kc*32..+31 (1024 float4)
        for (int idx = tid; idx < 1024; idx += 256)
            *(float4*)(&Wl[idx * 4]) = *(const float4*)(W + (size_t)kc * 32 * FDIM + idx * 4);
        __syncthreads();
        #pragma unroll
        for (int k4 = 0; k4 < 8; k4++) {        // 4 k at a time
            float4 xr[4];
            #pragma unroll
            for (int a = 0; a < 4; a++)
                xr[a] = *(const float4*)(&Xl[(rg + 32 * a) * 36 + k4 * 4]);
            #pragma unroll
            for (int kk = 0; kk < 4; kk++) {
                float xs[4];
                #pragma unroll
                for (int a = 0; a < 4; a++)
                    xs[a] = (kk == 0) ? xr[a].x : (kk == 1) ? xr[a].y
                          : (kk == 2) ? xr[a].z : xr[a].w;
                int k = k4 * 4 + kk;
                #pragma unroll
                for (int j = 0; j < 4; j++) {
                    float4 w = *(const float4*)(&Wl[k * FDIM + c0 + 32 * j]);
                    #pragma unroll
                    for (int a = 0; a < 4; a++) {
                        acc[a][j].x = fmaf(xs[a], w.x, acc[a][j].x);
                        acc[a][j].y = fmaf(xs[a], w.y, acc[a][j].y);
                        acc[a][j].z = fmaf(xs[a], w.z, acc[a][j].z);
                        acc[a][j].w = fmaf(xs[a], w.w, acc[a][j].w);
                    }
                }
            }
        }
    }
    #pragma unroll
    for (int a = 0; a < 4; a++) {
        int row = row0 + rg + 32 * a;
        if (row < nrows) {
            #pragma unroll
            for (int j = 0; j < 4; j++)
                *(float4*)(out + (size_t)row * FDIM + c0 + 32 * j) = acc[a][j];
        }
    }
}

// ---- Hierarchical exclusive scan ----------------------------------------
__global__ __launch_bounds__(256) void scan_block_sums(const int* __restrict__ cnt,
                                                       int* __restrict__ bsum, int n) {
    __shared__ int red[256];
    int tid = threadIdx.x;
    int idx = blockIdx.x * 256 + tid;
    red[tid] = (idx < n) ? cnt[idx] : 0;
    __syncthreads();
    for (int off = 128; off > 0; off >>= 1) {
        if (tid < off) red[tid] += red[tid + off];
        __syncthreads();
    }
    if (tid == 0) bsum[blockIdx.x] = red[0];
}

__global__ __launch_bounds__(1024) void scan_bsums(int* __restrict__ bsum, int nb) {
    __shared__ int sh[1024];
    int tid = threadIdx.x;
    int v = (tid < nb) ? bsum[tid] : 0;
    sh[tid] = v;
    __syncthreads();
    for (int off = 1; off < 1024; off <<= 1) {
        int t = (tid >= off) ? sh[tid - off] : 0;
        __syncthreads();
        sh[tid] += t;
        __syncthreads();
    }
    if (tid < nb) bsum[tid] = sh[tid] - v;   // exclusive
}

// also emits dinv = 1/sqrt(deg+1)
__global__ __launch_bounds__(256) void scan_final(const int* __restrict__ cnt,
                                                  const int* __restrict__ bsum,
                                                  int* __restrict__ rowptr,
                                                  int* __restrict__ cursor,
                                                  float* __restrict__ dinv, int n) {
    __shared__ int sh[256];
    int tid = threadIdx.x;
    int idx = blockIdx.x * 256 + tid;
    int c = (idx < n) ? cnt[idx] : 0;
    sh[tid] = c;
    __syncthreads();
    for (int off = 1; off < 256; off <<= 1) {
        int t = (tid >= off) ? sh[tid - off] : 0;
        __syncthreads();
        sh[tid] += t;
        __syncthreads();
    }
    if (idx < n) {
        int excl = sh[tid] - c + bsum[blockIdx.x];
        rowptr[idx] = excl;
        cursor[idx] = excl;
        dinv[idx] = 1.0f / sqrtf((float)(c + 1));
        if (idx == n - 1) rowptr[n] = excl + c;
    }
}

__global__ void scatter_kernel(const int* __restrict__ src, const int* __restrict__ dst,
                               int* __restrict__ cursor, int* __restrict__ csr_src, int ne) {
    int i = blockIdx.x * 256 + threadIdx.x;
    if (i < ne) {
        int d = dst[i];
        int pos = atomicAdd(&cursor[d], 1);
        csr_src[pos] = src[i];
    }
}

// ---- Aggregate + norm + bias + ELU --------------------------------------
__global__ __launch_bounds__(256) void agg_elu(const float* __restrict__ G,
                                               const int* __restrict__ rowptr,
                                               const int* __restrict__ csr_src,
                                               const float* __restrict__ dinv,
                                               const float* __restrict__ bias,
                                               float* __restrict__ out, int n) {
    int node = blockIdx.x * 8 + (threadIdx.x >> 5);
    int c = threadIdx.x & 31;
    if (node >= n) return;
    const float4* G4 = (const float4*)G;
    int beg = rowptr[node], end = rowptr[node + 1];
    float dn = dinv[node];
    float4 self = G4[(size_t)node * 32 + c];
    float4 acc;
    acc.x = dn * self.x; acc.y = dn * self.y; acc.z = dn * self.z; acc.w = dn * self.w;
    int e = beg;
    for (; e + 7 < end; e += 8) {
        int s0 = csr_src[e],     s1 = csr_src[e + 1], s2 = csr_src[e + 2], s3 = csr_src[e + 3];
        int s4 = csr_src[e + 4], s5 = csr_src[e + 5], s6 = csr_src[e + 6], s7 = csr_src[e + 7];
        float d0 = dinv[s0], d1 = dinv[s1], d2 = dinv[s2], d3 = dinv[s3];
        float d4 = dinv[s4], d5 = dinv[s5], d6 = dinv[s6], d7 = dinv[s7];
        float4 v0 = G4[(size_t)s0 * 32 + c];
        float4 v1 = G4[(size_t)s1 * 32 + c];
        float4 v2 = G4[(size_t)s2 * 32 + c];
        float4 v3 = G4[(size_t)s3 * 32 + c];
        float4 v4 = G4[(size_t)s4 * 32 + c];
        float4 v5 = G4[(size_t)s5 * 32 + c];
        float4 v6 = G4[(size_t)s6 * 32 + c];
        float4 v7 = G4[(size_t)s7 * 32 + c];
        acc.x = fmaf(d0, v0.x, acc.x); acc.y = fmaf(d0, v0.y, acc.y);
        acc.z = fmaf(d0, v0.z, acc.z); acc.w = fmaf(d0, v0.w, acc.w);
        acc.x = fmaf(d1, v1.x, acc.x); acc.y = fmaf(d1, v1.y, acc.y);
        acc.z = fmaf(d1, v1.z, acc.z); acc.w = fmaf(d1, v1.w, acc.w);
        acc.x = fmaf(d2, v2.x, acc.x); acc.y = fmaf(d2, v2.y, acc.y);
        acc.z = fmaf(d2, v2.z, acc.z); acc.w = fmaf(d2, v2.w, acc.w);
        acc.x = fmaf(d3, v3.x, acc.x); acc.y = fmaf(d3, v3.y, acc.y);
        acc.z = fmaf(d3, v3.z, acc.z); acc.w = fmaf(d3, v3.w, acc.w);
        acc.x = fmaf(d4, v4.x, acc.x); acc.y = fmaf(d4, v4.y, acc.y);
        acc.z = fmaf(d4, v4.z, acc.z); acc.w = fmaf(d4, v4.w, acc.w);
        acc.x = fmaf(d5, v5.x, acc.x); acc.y = fmaf(d5, v5.y, acc.y);
        acc.z = fmaf(d5, v5.z, acc.z); acc.w = fmaf(d5, v5.w, acc.w);
        acc.x = fmaf(d6, v6.x, acc.x); acc.y = fmaf(d6, v6.y, acc.y);
        acc.z = fmaf(d6, v6.z, acc.z); acc.w = fmaf(d6, v6.w, acc.w);
        acc.x = fmaf(d7, v7.x, acc.x); acc.y = fmaf(d7, v7.y, acc.y);
        acc.z = fmaf(d7, v7.z, acc.z); acc.w = fmaf(d7, v7.w, acc.w);
    }
    for (; e < end; e++) {
        int s = csr_src[e];
        float d = dinv[s];
        float4 v = G4[(size_t)s * 32 + c];
        acc.x = fmaf(d, v.x, acc.x); acc.y = fmaf(d, v.y, acc.y);
        acc.z = fmaf(d, v.z, acc.z); acc.w = fmaf(d, v.w, acc.w);
    }
    float4 b = ((const float4*)bias)[c];
    float4 r;
    r.x = fmaf(dn, acc.x, b.x); r.y = fmaf(dn, acc.y, b.y);
    r.z = fmaf(dn, acc.z, b.z); r.w = fmaf(dn, acc.w, b.w);
    r.x = (r.x > 0.f) ? r.x : expm1f(r.x);
    r.y = (r.y > 0.f) ? r.y : expm1f(r.y);
    r.z = (r.z > 0.f) ? r.z : expm1f(r.z);
    r.w = (r.w > 0.f) ? r.w : expm1f(r.w);
    ((float4*)out)[(size_t)node * 32 + c] = r;
}

// ---- Global mean pool (contiguous nper-node graphs) ---------------------
__global__ __launch_bounds__(256) void pool_kernel(const float* __restrict__ H,
                                                   float* __restrict__ out,
                                                   int nper, int ngraphs) {
    __shared__ float tmp[128];
    int g = blockIdx.x;
    int f = threadIdx.x & 127;
    int half = threadIdx.x >> 7;
    if (g >= ngraphs) return;
    const float* base = H + (size_t)g * nper * FDIM;
    float acc = 0.f;
    for (int i = half; i < nper; i += 2) acc += base[(size_t)i * FDIM + f];
    if (half == 1) tmp[f] = acc;
    __syncthreads();
    if (half == 0) out[(size_t)g * FDIM + f] = (acc + tmp[f]) * (1.0f / (float)nper);
}

extern "C" void kernel_launch(void* const* d_in, const int* in_sizes, int n_in,
                              void* d_out, int out_size, void* d_ws, size_t ws_size,
                              hipStream_t stream) {
    const float* x  = (const float*)d_in[0];
    const float* W1 = (const float*)d_in[1];
    const float* b1 = (const float*)d_in[2];
    const float* W2 = (const float*)d_in[3];
    const float* b2 = (const float*)d_in[4];
    const int* edge_index = (const int*)d_in[5];
    float* out = (float*)d_out;

    int N = in_sizes[0] / FDIM;
    int E = in_sizes[5] / 2;
    int G = out_size / FDIM;
    int nper = N / G;
    const int* src = edge_index;
    const int* dst = edge_index + E;

    char* ws = (char*)d_ws;
    size_t off = 0;
    int* cnt = (int*)(ws + off);       off = align512(off + (size_t)N * 4);
    int* rowptr = (int*)(ws + off);    off = align512(off + (size_t)(N + 1) * 4);
    int* cursor = (int*)(ws + off);    off = align512(off + (size_t)N * 4);
    float* dinv = (float*)(ws + off);  off = align512(off + (size_t)N * 4);
    int* bsum = (int*)(ws + off);      off = align512(off + (size_t)1024 * 4);
    int* csr_src = (int*)(ws + off);   off = align512(off + (size_t)E * 4);
    float* bufA = (float*)(ws + off);  off = align512(off + (size_t)N * FDIM * 4);
    float* bufB = (float*)(ws + off);  off = align512(off + (size_t)N * FDIM * 4);
    (void)ws_size;

    int nb = (N + 255) / 256;                    // scan blocks (<=1024)
    int gemm_grid = (N + TROWS - 1) / TROWS;     // 391
    int cnt_grid = (E + 255) / 256;
    int agg_grid = (N + 7) / 8;

    hipMemsetAsync(cnt, 0, (size_t)N * 4, stream);
    // layer-1 GEMM fused with degree histogram (independent work)
    gemm_count<<<gemm_grid + cnt_grid, 256, 0, stream>>>(x, W1, bufA, N,
                                                         gemm_grid, dst, cnt, E);
    scan_block_sums<<<nb, 256, 0, stream>>>(cnt, bsum, N);
    scan_bsums<<<1, 1024, 0, stream>>>(bsum, nb);
    scan_final<<<nb, 256, 0, stream>>>(cnt, bsum, rowptr, cursor, dinv, N);
    scatter_kernel<<<(E + 255) / 256, 256, 0, stream>>>(src, dst, cursor, csr_src, E);

    agg_elu<<<agg_grid, 256, 0, stream>>>(bufA, rowptr, csr_src, dinv, b1, bufB, N);
    // layer-2 GEMM (no count part)
    gemm_count<<<gemm_grid, 256, 0, stream>>>(bufB, W2, bufA, N, gemm_grid, dst, cnt, 0);
    agg_elu<<<agg_grid, 256, 0, stream>>>(bufA, rowptr, csr_src, dinv, b2, bufB, N);
    pool_kernel<<<G, 256, 0, stream>>>(bufB, out, nper, G);
}

// Round 6
// 284.687 us; speedup vs baseline: 1.3779x; 1.0019x over previous
//
#include <hip/hip_runtime.h>
#include <math.h>

#define FDIM 128

static inline size_t align512(size_t x) { return (x + 511) & ~((size_t)511); }

// ---- fused GEMM (out = X@W, unscaled) + optional degree histogram -------
// GEMM: 128 rows/block, 256 threads, thread = 4 rows x 16 cols.
// K processed in 4 chunks of 32; LDS = X[128][36] + W[32][128] = 34.8 KB.
// NOTE: no min-waves clause — 64 f32 accumulators need ~110 VGPR; capping
// at 64 (R4) spilled acc to scratch (WRITE_SIZE 131MB, 119us).
#define TROWS 128
__global__ __launch_bounds__(256) void gemm_count(const float* __restrict__ X,
                                                  const float* __restrict__ W,
                                                  float* __restrict__ out, int nrows,
                                                  int gemm_blocks,
                                                  const int* __restrict__ dst,
                                                  int* __restrict__ cnt, int ne) {
    __shared__ __align__(16) float Xl[TROWS * 36];   // one 32-k slice of X, pad->36
    __shared__ __align__(16) float Wl[32 * 128];     // one 32-k slice of W
    if ((int)blockIdx.x >= gemm_blocks) {
        int i = ((int)blockIdx.x - gemm_blocks) * 256 + threadIdx.x;
        if (i < ne) atomicAdd(&cnt[dst[i]], 1);
        return;
    }
    int tid = threadIdx.x;
    int row0 = blockIdx.x * TROWS;
    int nrow_t = min(TROWS, nrows - row0);

    int rg = tid >> 3;           // 0..31 -> rows rg, rg+32, rg+64, rg+96
    int c0 = (tid & 7) * 4;      // col base; cols c0 + 32*j
    float4 acc[4][4];
    #pragma unroll
    for (int a = 0; a < 4; a++)
        #pragma unroll
        for (int j = 0; j < 4; j++) acc[a][j] = make_float4(0.f, 0.f, 0.f, 0.f);

    for (int kc = 0; kc < 4; kc++) {
        __syncthreads();
        for (int idx = tid; idx < nrow_t * 8; idx += 256) {
            int r = idx >> 3, c4 = idx & 7;
            *(float4*)(&Xl[r * 36 + c4 * 4]) =
                *(const float4*)(X + (size_t)(row0 + r) * FDIM + kc * 32 + c4 * 4);
        }
        for (int idx = tid; idx < 1024; idx += 256)
            *(float4*)(&Wl[idx * 4]) = *(const float4*)(W + (size_t)kc * 32 * FDIM + idx * 4);
        __syncthreads();
        #pragma unroll
        for (int k4 = 0; k4 < 8; k4++) {        // 4 k at a time
            float4 xr[4];
            #pragma unroll
            for (int a = 0; a < 4; a++)
                xr[a] = *(const float4*)(&Xl[(rg + 32 * a) * 36 + k4 * 4]);
            #pragma unroll
            for (int kk = 0; kk < 4; kk++) {
                float xs[4];
                #pragma unroll
                for (int a = 0; a < 4; a++)
                    xs[a] = (kk == 0) ? xr[a].x : (kk == 1) ? xr[a].y
                          : (kk == 2) ? xr[a].z : xr[a].w;
                int k = k4 * 4 + kk;
                #pragma unroll
                for (int j = 0; j < 4; j++) {
                    float4 w = *(const float4*)(&Wl[k * FDIM + c0 + 32 * j]);
                    #pragma unroll
                    for (int a = 0; a < 4; a++) {
                        acc[a][j].x = fmaf(xs[a], w.x, acc[a][j].x);
                        acc[a][j].y = fmaf(xs[a], w.y, acc[a][j].y);
                        acc[a][j].z = fmaf(xs[a], w.z, acc[a][j].z);
                        acc[a][j].w = fmaf(xs[a], w.w, acc[a][j].w);
                    }
                }
            }
        }
    }
    #pragma unroll
    for (int a = 0; a < 4; a++) {
        int row = row0 + rg + 32 * a;
        if (row < nrows) {
            #pragma unroll
            for (int j = 0; j < 4; j++)
                *(float4*)(out + (size_t)row * FDIM + c0 + 32 * j) = acc[a][j];
        }
    }
}

// ---- Hierarchical exclusive scan ----------------------------------------
__global__ __launch_bounds__(256) void scan_block_sums(const int* __restrict__ cnt,
                                                       int* __restrict__ bsum, int n) {
    __shared__ int red[256];
    int tid = threadIdx.x;
    int idx = blockIdx.x * 256 + tid;
    red[tid] = (idx < n) ? cnt[idx] : 0;
    __syncthreads();
    for (int off = 128; off > 0; off >>= 1) {
        if (tid < off) red[tid] += red[tid + off];
        __syncthreads();
    }
    if (tid == 0) bsum[blockIdx.x] = red[0];
}

__global__ __launch_bounds__(1024) void scan_bsums(int* __restrict__ bsum, int nb) {
    __shared__ int sh[1024];
    int tid = threadIdx.x;
    int v = (tid < nb) ? bsum[tid] : 0;
    sh[tid] = v;
    __syncthreads();
    for (int off = 1; off < 1024; off <<= 1) {
        int t = (tid >= off) ? sh[tid - off] : 0;
        __syncthreads();
        sh[tid] += t;
        __syncthreads();
    }
    if (tid < nb) bsum[tid] = sh[tid] - v;   // exclusive
}

// also emits dinv = 1/sqrt(deg+1)
__global__ __launch_bounds__(256) void scan_final(const int* __restrict__ cnt,
                                                  const int* __restrict__ bsum,
                                                  int* __restrict__ rowptr,
                                                  int* __restrict__ cursor,
                                                  float* __restrict__ dinv, int n) {
    __shared__ int sh[256];
    int tid = threadIdx.x;
    int idx = blockIdx.x * 256 + tid;
    int c = (idx < n) ? cnt[idx] : 0;
    sh[tid] = c;
    __syncthreads();
    for (int off = 1; off < 256; off <<= 1) {
        int t = (tid >= off) ? sh[tid - off] : 0;
        __syncthreads();
        sh[tid] += t;
        __syncthreads();
    }
    if (idx < n) {
        int excl = sh[tid] - c + bsum[blockIdx.x];
        rowptr[idx] = excl;
        cursor[idx] = excl;
        dinv[idx] = 1.0f / sqrtf((float)(c + 1));
        if (idx == n - 1) rowptr[n] = excl + c;
    }
}

// writes packed (src, dinv[src]) per CSR slot -> hot loop reads sequentially
__global__ void scatter_kernel(const int* __restrict__ src, const int* __restrict__ dst,
                               const float* __restrict__ dinv,
                               int* __restrict__ cursor, int2* __restrict__ csr_pack,
                               int ne) {
    int i = blockIdx.x * 256 + threadIdx.x;
    if (i < ne) {
        int d = dst[i];
        int s = src[i];
        int pos = atomicAdd(&cursor[d], 1);
        int2 p;
        p.x = s;
        p.y = __float_as_int(dinv[s]);
        csr_pack[pos] = p;
    }
}

// ---- Aggregate + norm + bias + ELU --------------------------------------
// out[i] = elu( dinv[i] * ( sum_e dinv[s_e]*G[s_e] + dinv[i]*G[i] ) + b )
// 8 nodes/block, 32 threads/node, float4/lane, edge loop unrolled x8.
// (src, dinv_src) read sequentially from csr_pack -> single random level.
__global__ __launch_bounds__(256) void agg_elu(const float* __restrict__ G,
                                               const int* __restrict__ rowptr,
                                               const int2* __restrict__ csr_pack,
                                               const float* __restrict__ dinv,
                                               const float* __restrict__ bias,
                                               float* __restrict__ out, int n) {
    int node = blockIdx.x * 8 + (threadIdx.x >> 5);
    int c = threadIdx.x & 31;
    if (node >= n) return;
    const float4* G4 = (const float4*)G;
    int beg = rowptr[node], end = rowptr[node + 1];
    float dn = dinv[node];
    float4 self = G4[(size_t)node * 32 + c];
    float4 acc;
    acc.x = dn * self.x; acc.y = dn * self.y; acc.z = dn * self.z; acc.w = dn * self.w;
    int e = beg;
    for (; e + 7 < end; e += 8) {
        int2 p0 = csr_pack[e],     p1 = csr_pack[e + 1];
        int2 p2 = csr_pack[e + 2], p3 = csr_pack[e + 3];
        int2 p4 = csr_pack[e + 4], p5 = csr_pack[e + 5];
        int2 p6 = csr_pack[e + 6], p7 = csr_pack[e + 7];
        float4 v0 = G4[(size_t)p0.x * 32 + c];
        float4 v1 = G4[(size_t)p1.x * 32 + c];
        float4 v2 = G4[(size_t)p2.x * 32 + c];
        float4 v3 = G4[(size_t)p3.x * 32 + c];
        float4 v4 = G4[(size_t)p4.x * 32 + c];
        float4 v5 = G4[(size_t)p5.x * 32 + c];
        float4 v6 = G4[(size_t)p6.x * 32 + c];
        float4 v7 = G4[(size_t)p7.x * 32 + c];
        float d0 = __int_as_float(p0.y), d1 = __int_as_float(p1.y);
        float d2 = __int_as_float(p2.y), d3 = __int_as_float(p3.y);
        float d4 = __int_as_float(p4.y), d5 = __int_as_float(p5.y);
        float d6 = __int_as_float(p6.y), d7 = __int_as_float(p7.y);
        acc.x = fmaf(d0, v0.x, acc.x); acc.y = fmaf(d0, v0.y, acc.y);
        acc.z = fmaf(d0, v0.z, acc.z); acc.w = fmaf(d0, v0.w, acc.w);
        acc.x = fmaf(d1, v1.x, acc.x); acc.y = fmaf(d1, v1.y, acc.y);
        acc.z = fmaf(d1, v1.z, acc.z); acc.w = fmaf(d1, v1.w, acc.w);
        acc.x = fmaf(d2, v2.x, acc.x); acc.y = fmaf(d2, v2.y, acc.y);
        acc.z = fmaf(d2, v2.z, acc.z); acc.w = fmaf(d2, v2.w, acc.w);
        acc.x = fmaf(d3, v3.x, acc.x); acc.y = fmaf(d3, v3.y, acc.y);
        acc.z = fmaf(d3, v3.z, acc.z); acc.w = fmaf(d3, v3.w, acc.w);
        acc.x = fmaf(d4, v4.x, acc.x); acc.y = fmaf(d4, v4.y, acc.y);
        acc.z = fmaf(d4, v4.z, acc.z); acc.w = fmaf(d4, v4.w, acc.w);
        acc.x = fmaf(d5, v5.x, acc.x); acc.y = fmaf(d5, v5.y, acc.y);
        acc.z = fmaf(d5, v5.z, acc.z); acc.w = fmaf(d5, v5.w, acc.w);
        acc.x = fmaf(d6, v6.x, acc.x); acc.y = fmaf(d6, v6.y, acc.y);
        acc.z = fmaf(d6, v6.z, acc.z); acc.w = fmaf(d6, v6.w, acc.w);
        acc.x = fmaf(d7, v7.x, acc.x); acc.y = fmaf(d7, v7.y, acc.y);
        acc.z = fmaf(d7, v7.z, acc.z); acc.w = fmaf(d7, v7.w, acc.w);
    }
    for (; e < end; e++) {
        int2 p = csr_pack[e];
        float d = __int_as_float(p.y);
        float4 v = G4[(size_t)p.x * 32 + c];
        acc.x = fmaf(d, v.x, acc.x); acc.y = fmaf(d, v.y, acc.y);
        acc.z = fmaf(d, v.z, acc.z); acc.w = fmaf(d, v.w, acc.w);
    }
    float4 b = ((const float4*)bias)[c];
    float4 r;
    r.x = fmaf(dn, acc.x, b.x); r.y = fmaf(dn, acc.y, b.y);
    r.z = fmaf(dn, acc.z, b.z); r.w = fmaf(dn, acc.w, b.w);
    r.x = (r.x > 0.f) ? r.x : expm1f(r.x);
    r.y = (r.y > 0.f) ? r.y : expm1f(r.y);
    r.z = (r.z > 0.f) ? r.z : expm1f(r.z);
    r.w = (r.w > 0.f) ? r.w : expm1f(r.w);
    ((float4*)out)[(size_t)node * 32 + c] = r;
}

// ---- Global mean pool (contiguous nper-node graphs) ---------------------
__global__ __launch_bounds__(256) void pool_kernel(const float* __restrict__ H,
                                                   float* __restrict__ out,
                                                   int nper, int ngraphs) {
    __shared__ float tmp[128];
    int g = blockIdx.x;
    int f = threadIdx.x & 127;
    int half = threadIdx.x >> 7;
    if (g >= ngraphs) return;
    const float* base = H + (size_t)g * nper * FDIM;
    float acc = 0.f;
    for (int i = half; i < nper; i += 2) acc += base[(size_t)i * FDIM + f];
    if (half == 1) tmp[f] = acc;
    __syncthreads();
    if (half == 0) out[(size_t)g * FDIM + f] = (acc + tmp[f]) * (1.0f / (float)nper);
}

extern "C" void kernel_launch(void* const* d_in, const int* in_sizes, int n_in,
                              void* d_out, int out_size, void* d_ws, size_t ws_size,
                              hipStream_t stream) {
    const float* x  = (const float*)d_in[0];
    const float* W1 = (const float*)d_in[1];
    const float* b1 = (const float*)d_in[2];
    const float* W2 = (const float*)d_in[3];
    const float* b2 = (const float*)d_in[4];
    const int* edge_index = (const int*)d_in[5];
    float* out = (float*)d_out;

    int N = in_sizes[0] / FDIM;
    int E = in_sizes[5] / 2;
    int G = out_size / FDIM;
    int nper = N / G;
    const int* src = edge_index;
    const int* dst = edge_index + E;

    char* ws = (char*)d_ws;
    size_t off = 0;
    int* cnt = (int*)(ws + off);        off = align512(off + (size_t)N * 4);
    int* rowptr = (int*)(ws + off);     off = align512(off + (size_t)(N + 1) * 4);
    int* cursor = (int*)(ws + off);     off = align512(off + (size_t)N * 4);
    float* dinv = (float*)(ws + off);   off = align512(off + (size_t)N * 4);
    int* bsum = (int*)(ws + off);       off = align512(off + (size_t)1024 * 4);
    int2* csr_pack = (int2*)(ws + off); off = align512(off + (size_t)E * 8);
    float* bufA = (float*)(ws + off);   off = align512(off + (size_t)N * FDIM * 4);
    float* bufB = (float*)(ws + off);   off = align512(off + (size_t)N * FDIM * 4);
    (void)ws_size;

    int nb = (N + 255) / 256;                    // scan blocks (<=1024)
    int gemm_grid = (N + TROWS - 1) / TROWS;     // 391
    int cnt_grid = (E + 255) / 256;
    int agg_grid = (N + 7) / 8;

    hipMemsetAsync(cnt, 0, (size_t)N * 4, stream);
    // layer-1 GEMM fused with degree histogram (independent work)
    gemm_count<<<gemm_grid + cnt_grid, 256, 0, stream>>>(x, W1, bufA, N,
                                                         gemm_grid, dst, cnt, E);
    scan_block_sums<<<nb, 256, 0, stream>>>(cnt, bsum, N);
    scan_bsums<<<1, 1024, 0, stream>>>(bsum, nb);
    scan_final<<<nb, 256, 0, stream>>>(cnt, bsum, rowptr, cursor, dinv, N);
    scatter_kernel<<<(E + 255) / 256, 256, 0, stream>>>(src, dst, dinv, cursor,
                                                        csr_pack, E);

    agg_elu<<<agg_grid, 256, 0, stream>>>(bufA, rowptr, csr_pack, dinv, b1, bufB, N);
    // layer-2 GEMM (no count part)
    gemm_count<<<gemm_grid, 256, 0, stream>>>(bufB, W2, bufA, N, gemm_grid, dst, cnt, 0);
    agg_elu<<<agg_grid, 256, 0, stream>>>(bufA, rowptr, csr_pack, dinv, b2, bufB, N);
    pool_kernel<<<G, 256, 0, stream>>>(bufB, out, nper, G);
}

// Round 7
// 227.247 us; speedup vs baseline: 1.7261x; 1.2528x over previous
//
#include <hip/hip_runtime.h>
#include <hip/hip_fp16.h>
#include <math.h>

#define FDIM 128

static inline size_t align512(size_t x) { return (x + 511) & ~((size_t)511); }

// ---- fused GEMM (out_fp16 = X@W) + optional degree histogram ------------
// GEMM: 128 rows/block, 256 threads, thread = 4 rows x 16 cols.
// K in 4 chunks of 32; LDS = X[128][36] + W[32][128] = 34.8 KB.
// Output stored fp16: gathered matrix G is read randomly by agg_elu; halving
// row bytes (512->256) halves the L3 gather traffic (R6: agg is L3-BW-bound).
// NOTE: no min-waves clause — 64 f32 accumulators; capping VGPR at 64 (R4)
// spilled acc to scratch (WRITE_SIZE 131MB, 119us).
#define TROWS 128
__global__ __launch_bounds__(256) void gemm_count(const float* __restrict__ X,
                                                  const float* __restrict__ W,
                                                  __half* __restrict__ out, int nrows,
                                                  int gemm_blocks,
                                                  const int* __restrict__ dst,
                                                  int* __restrict__ cnt, int ne) {
    __shared__ __align__(16) float Xl[TROWS * 36];   // one 32-k slice of X, pad->36
    __shared__ __align__(16) float Wl[32 * 128];     // one 32-k slice of W
    if ((int)blockIdx.x >= gemm_blocks) {
        int i = ((int)blockIdx.x - gemm_blocks) * 256 + threadIdx.x;
        if (i < ne) atomicAdd(&cnt[dst[i]], 1);
        return;
    }
    int tid = threadIdx.x;
    int row0 = blockIdx.x * TROWS;
    int nrow_t = min(TROWS, nrows - row0);

    int rg = tid >> 3;           // 0..31 -> rows rg, rg+32, rg+64, rg+96
    int c0 = (tid & 7) * 4;      // col base; cols c0 + 32*j
    float4 acc[4][4];
    #pragma unroll
    for (int a = 0; a < 4; a++)
        #pragma unroll
        for (int j = 0; j < 4; j++) acc[a][j] = make_float4(0.f, 0.f, 0.f, 0.f);

    for (int kc = 0; kc < 4; kc++) {
        __syncthreads();
        for (int idx = tid; idx < nrow_t * 8; idx += 256) {
            int r = idx >> 3, c4 = idx & 7;
            *(float4*)(&Xl[r * 36 + c4 * 4]) =
                *(const float4*)(X + (size_t)(row0 + r) * FDIM + kc * 32 + c4 * 4);
        }
        for (int idx = tid; idx < 1024; idx += 256)
            *(float4*)(&Wl[idx * 4]) = *(const float4*)(W + (size_t)kc * 32 * FDIM + idx * 4);
        __syncthreads();
        #pragma unroll
        for (int k4 = 0; k4 < 8; k4++) {        // 4 k at a time
            float4 xr[4];
            #pragma unroll
            for (int a = 0; a < 4; a++)
                xr[a] = *(const float4*)(&Xl[(rg + 32 * a) * 36 + k4 * 4]);
            #pragma unroll
            for (int kk = 0; kk < 4; kk++) {
                float xs[4];
                #pragma unroll
                for (int a = 0; a < 4; a++)
                    xs[a] = (kk == 0) ? xr[a].x : (kk == 1) ? xr[a].y
                          : (kk == 2) ? xr[a].z : xr[a].w;
                int k = k4 * 4 + kk;
                #pragma unroll
                for (int j = 0; j < 4; j++) {
                    float4 w = *(const float4*)(&Wl[k * FDIM + c0 + 32 * j]);
                    #pragma unroll
                    for (int a = 0; a < 4; a++) {
                        acc[a][j].x = fmaf(xs[a], w.x, acc[a][j].x);
                        acc[a][j].y = fmaf(xs[a], w.y, acc[a][j].y);
                        acc[a][j].z = fmaf(xs[a], w.z, acc[a][j].z);
                        acc[a][j].w = fmaf(xs[a], w.w, acc[a][j].w);
                    }
                }
            }
        }
    }
    #pragma unroll
    for (int a = 0; a < 4; a++) {
        int row = row0 + rg + 32 * a;
        if (row < nrows) {
            #pragma unroll
            for (int j = 0; j < 4; j++) {
                __half2 h0 = __floats2half2_rn(acc[a][j].x, acc[a][j].y);
                __half2 h1 = __floats2half2_rn(acc[a][j].z, acc[a][j].w);
                __half2* p = (__half2*)(out + (size_t)row * FDIM + c0 + 32 * j);
                p[0] = h0; p[1] = h1;
            }
        }
    }
}

// ---- Hierarchical exclusive scan ----------------------------------------
__global__ __launch_bounds__(256) void scan_block_sums(const int* __restrict__ cnt,
                                                       int* __restrict__ bsum, int n) {
    __shared__ int red[256];
    int tid = threadIdx.x;
    int idx = blockIdx.x * 256 + tid;
    red[tid] = (idx < n) ? cnt[idx] : 0;
    __syncthreads();
    for (int off = 128; off > 0; off >>= 1) {
        if (tid < off) red[tid] += red[tid + off];
        __syncthreads();
    }
    if (tid == 0) bsum[blockIdx.x] = red[0];
}

__global__ __launch_bounds__(1024) void scan_bsums(int* __restrict__ bsum, int nb) {
    __shared__ int sh[1024];
    int tid = threadIdx.x;
    int v = (tid < nb) ? bsum[tid] : 0;
    sh[tid] = v;
    __syncthreads();
    for (int off = 1; off < 1024; off <<= 1) {
        int t = (tid >= off) ? sh[tid - off] : 0;
        __syncthreads();
        sh[tid] += t;
        __syncthreads();
    }
    if (tid < nb) bsum[tid] = sh[tid] - v;   // exclusive
}

// also emits dinv = 1/sqrt(deg+1)
__global__ __launch_bounds__(256) void scan_final(const int* __restrict__ cnt,
                                                  const int* __restrict__ bsum,
                                                  int* __restrict__ rowptr,
                                                  int* __restrict__ cursor,
                                                  float* __restrict__ dinv, int n) {
    __shared__ int sh[256];
    int tid = threadIdx.x;
    int idx = blockIdx.x * 256 + tid;
    int c = (idx < n) ? cnt[idx] : 0;
    sh[tid] = c;
    __syncthreads();
    for (int off = 1; off < 256; off <<= 1) {
        int t = (tid >= off) ? sh[tid - off] : 0;
        __syncthreads();
        sh[tid] += t;
        __syncthreads();
    }
    if (idx < n) {
        int excl = sh[tid] - c + bsum[blockIdx.x];
        rowptr[idx] = excl;
        cursor[idx] = excl;
        dinv[idx] = 1.0f / sqrtf((float)(c + 1));
        if (idx == n - 1) rowptr[n] = excl + c;
    }
}

// writes packed (src, dinv[src]) per CSR slot
__global__ void scatter_kernel(const int* __restrict__ src, const int* __restrict__ dst,
                               const float* __restrict__ dinv,
                               int* __restrict__ cursor, int2* __restrict__ csr_pack,
                               int ne) {
    int i = blockIdx.x * 256 + threadIdx.x;
    if (i < ne) {
        int d = dst[i];
        int s = src[i];
        int pos = atomicAdd(&cursor[d], 1);
        int2 p;
        p.x = s;
        p.y = __float_as_int(dinv[s]);
        csr_pack[pos] = p;
    }
}

// ---- Aggregate + norm + bias + ELU --------------------------------------
// G is fp16 (row = 256 B); 8 nodes/block, 32 threads/node, 8 B/lane,
// edge loop unrolled x8. acc/output fp32.
__global__ __launch_bounds__(256) void agg_elu(const __half* __restrict__ G,
                                               const int* __restrict__ rowptr,
                                               const int2* __restrict__ csr_pack,
                                               const float* __restrict__ dinv,
                                               const float* __restrict__ bias,
                                               float* __restrict__ out, int n) {
    int node = blockIdx.x * 8 + (threadIdx.x >> 5);
    int c = threadIdx.x & 31;
    if (node >= n) return;
    const float2* G2 = (const float2*)G;   // 8 B units; row stride = 32
    int beg = rowptr[node], end = rowptr[node + 1];
    float dn = dinv[node];

    float2 sraw = G2[(size_t)node * 32 + c];
    __half2 sh0 = *(__half2*)&sraw.x, sh1 = *(__half2*)&sraw.y;
    float2 s0f = __half22float2(sh0), s1f = __half22float2(sh1);
    float4 acc;
    acc.x = dn * s0f.x; acc.y = dn * s0f.y; acc.z = dn * s1f.x; acc.w = dn * s1f.y;

    int e = beg;
    for (; e + 7 < end; e += 8) {
        int2 p0 = csr_pack[e],     p1 = csr_pack[e + 1];
        int2 p2 = csr_pack[e + 2], p3 = csr_pack[e + 3];
        int2 p4 = csr_pack[e + 4], p5 = csr_pack[e + 5];
        int2 p6 = csr_pack[e + 6], p7 = csr_pack[e + 7];
        float2 r0 = G2[(size_t)p0.x * 32 + c];
        float2 r1 = G2[(size_t)p1.x * 32 + c];
        float2 r2 = G2[(size_t)p2.x * 32 + c];
        float2 r3 = G2[(size_t)p3.x * 32 + c];
        float2 r4 = G2[(size_t)p4.x * 32 + c];
        float2 r5 = G2[(size_t)p5.x * 32 + c];
        float2 r6 = G2[(size_t)p6.x * 32 + c];
        float2 r7 = G2[(size_t)p7.x * 32 + c];
        #define ACC_EDGE(P, R)                                              \
        {                                                                   \
            float d = __int_as_float(P.y);                                  \
            __half2 h0 = *(__half2*)&R.x, h1 = *(__half2*)&R.y;             \
            float2 f0 = __half22float2(h0), f1 = __half22float2(h1);        \
            acc.x = fmaf(d, f0.x, acc.x); acc.y = fmaf(d, f0.y, acc.y);     \
            acc.z = fmaf(d, f1.x, acc.z); acc.w = fmaf(d, f1.y, acc.w);     \
        }
        ACC_EDGE(p0, r0) ACC_EDGE(p1, r1) ACC_EDGE(p2, r2) ACC_EDGE(p3, r3)
        ACC_EDGE(p4, r4) ACC_EDGE(p5, r5) ACC_EDGE(p6, r6) ACC_EDGE(p7, r7)
    }
    for (; e < end; e++) {
        int2 p = csr_pack[e];
        float2 r = G2[(size_t)p.x * 32 + c];
        ACC_EDGE(p, r)
    }
    #undef ACC_EDGE

    float4 b = ((const float4*)bias)[c];
    float4 o;
    o.x = fmaf(dn, acc.x, b.x); o.y = fmaf(dn, acc.y, b.y);
    o.z = fmaf(dn, acc.z, b.z); o.w = fmaf(dn, acc.w, b.w);
    o.x = (o.x > 0.f) ? o.x : expm1f(o.x);
    o.y = (o.y > 0.f) ? o.y : expm1f(o.y);
    o.z = (o.z > 0.f) ? o.z : expm1f(o.z);
    o.w = (o.w > 0.f) ? o.w : expm1f(o.w);
    ((float4*)out)[(size_t)node * 32 + c] = o;
}

// ---- Global mean pool (contiguous nper-node graphs) ---------------------
__global__ __launch_bounds__(256) void pool_kernel(const float* __restrict__ H,
                                                   float* __restrict__ out,
                                                   int nper, int ngraphs) {
    __shared__ float tmp[128];
    int g = blockIdx.x;
    int f = threadIdx.x & 127;
    int half = threadIdx.x >> 7;
    if (g >= ngraphs) return;
    const float* base = H + (size_t)g * nper * FDIM;
    float acc = 0.f;
    for (int i = half; i < nper; i += 2) acc += base[(size_t)i * FDIM + f];
    if (half == 1) tmp[f] = acc;
    __syncthreads();
    if (half == 0) out[(size_t)g * FDIM + f] = (acc + tmp[f]) * (1.0f / (float)nper);
}

extern "C" void kernel_launch(void* const* d_in, const int* in_sizes, int n_in,
                              void* d_out, int out_size, void* d_ws, size_t ws_size,
                              hipStream_t stream) {
    const float* x  = (const float*)d_in[0];
    const float* W1 = (const float*)d_in[1];
    const float* b1 = (const float*)d_in[2];
    const float* W2 = (const float*)d_in[3];
    const float* b2 = (const float*)d_in[4];
    const int* edge_index = (const int*)d_in[5];
    float* out = (float*)d_out;

    int N = in_sizes[0] / FDIM;
    int E = in_sizes[5] / 2;
    int G = out_size / FDIM;
    int nper = N / G;
    const int* src = edge_index;
    const int* dst = edge_index + E;

    char* ws = (char*)d_ws;
    size_t off = 0;
    int* cnt = (int*)(ws + off);        off = align512(off + (size_t)N * 4);
    int* rowptr = (int*)(ws + off);     off = align512(off + (size_t)(N + 1) * 4);
    int* cursor = (int*)(ws + off);     off = align512(off + (size_t)N * 4);
    float* dinv = (float*)(ws + off);   off = align512(off + (size_t)N * 4);
    int* bsum = (int*)(ws + off);       off = align512(off + (size_t)1024 * 4);
    int2* csr_pack = (int2*)(ws + off); off = align512(off + (size_t)E * 8);
    __half* bufG = (__half*)(ws + off); off = align512(off + (size_t)N * FDIM * 2);
    float* bufB = (float*)(ws + off);   off = align512(off + (size_t)N * FDIM * 4);
    (void)ws_size;

    int nb = (N + 255) / 256;                    // scan blocks (<=1024)
    int gemm_grid = (N + TROWS - 1) / TROWS;
    int cnt_grid = (E + 255) / 256;
    int agg_grid = (N + 7) / 8;

    hipMemsetAsync(cnt, 0, (size_t)N * 4, stream);
    // layer-1 GEMM fused with degree histogram (independent work)
    gemm_count<<<gemm_grid + cnt_grid, 256, 0, stream>>>(x, W1, bufG, N,
                                                         gemm_grid, dst, cnt, E);
    scan_block_sums<<<nb, 256, 0, stream>>>(cnt, bsum, N);
    scan_bsums<<<1, 1024, 0, stream>>>(bsum, nb);
    scan_final<<<nb, 256, 0, stream>>>(cnt, bsum, rowptr, cursor, dinv, N);
    scatter_kernel<<<(E + 255) / 256, 256, 0, stream>>>(src, dst, dinv, cursor,
                                                        csr_pack, E);

    agg_elu<<<agg_grid, 256, 0, stream>>>(bufG, rowptr, csr_pack, dinv, b1, bufB, N);
    // layer-2 GEMM (no count part)
    gemm_count<<<gemm_grid, 256, 0, stream>>>(bufB, W2, bufG, N, gemm_grid, dst, cnt, 0);
    agg_elu<<<agg_grid, 256, 0, stream>>>(bufG, rowptr, csr_pack, dinv, b2, bufB, N);
    pool_kernel<<<G, 256, 0, stream>>>(bufB, out, nper, G);
}